// Round 1
// baseline (267.582 us; speedup 1.0000x reference)
//
#include <hip/hip_runtime.h>
#include <hip/hip_bf16.h>

#define BATCH 2
#define SLEN 2048
#define NH 12
#define DM 768
#define DH 64
#define ROWS (BATCH*SLEN)   // 4096
#define NQKV (3*DM)         // 2304

typedef __attribute__((ext_vector_type(8))) short bf16x8;
typedef __attribute__((ext_vector_type(4))) float f32x4;
typedef unsigned short u16;
typedef __attribute__((ext_vector_type(4))) unsigned short u16x4;
typedef __attribute__((ext_vector_type(8))) unsigned short u16x8;

// fp32 -> bf16 RNE (values are finite; no NaN handling needed)
__device__ __forceinline__ u16 f2b(float f) {
    unsigned int u = __builtin_bit_cast(unsigned int, f);
    unsigned int r = (u + 0x7FFFu + ((u >> 16) & 1u)) >> 16;
    return (u16)r;
}

// ---------------- pack kernels ----------------

__global__ __launch_bounds__(256) void pack_x(const float* __restrict__ x, u16* __restrict__ xb) {
    int i = blockIdx.x * 256 + threadIdx.x;      // one thread per 8 floats
    const float4* xv = (const float4*)x;
    float4 a = xv[i * 2], b = xv[i * 2 + 1];
    u16x8 o;
    o[0] = f2b(a.x); o[1] = f2b(a.y); o[2] = f2b(a.z); o[3] = f2b(a.w);
    o[4] = f2b(b.x); o[5] = f2b(b.y); o[6] = f2b(b.z); o[7] = f2b(b.w);
    *(u16x8*)(xb + (size_t)i * 8) = o;
}

// W_{Q,K,V}[h][m][d] (f32) -> wqkv[(sel*768 + h*64 + d)][m] (bf16)  ("Bt" layout: K-contiguous)
__global__ __launch_bounds__(256) void pack_wqkv(const float* __restrict__ WQ, const float* __restrict__ WK,
                                                 const float* __restrict__ WV, u16* __restrict__ out) {
    __shared__ u16 L[64 * 72];
    int mt = blockIdx.x, h = blockIdx.y, sel = blockIdx.z;
    const float* W = sel == 0 ? WQ : (sel == 1 ? WK : WV);
    const float* src = W + ((size_t)h * DM + mt * 64) * DH;   // 64 rows (m) x 64 cols (d), contiguous
    int t = threadIdx.x;
    for (int j = 0; j < 4; j++) {
        int i = t + 256 * j;                 // 1024 float4s
        int r = i >> 4, cf = i & 15;
        float4 v = ((const float4*)src)[i];
        u16x4 o; o[0] = f2b(v.x); o[1] = f2b(v.y); o[2] = f2b(v.z); o[3] = f2b(v.w);
        *(u16x4*)&L[r * 72 + cf * 4] = o;
    }
    __syncthreads();
    u16* orow = out + ((size_t)(sel * DM + h * DH)) * DM + mt * 64;
    for (int j = 0; j < 16; j++) {
        int e = t + 256 * j;                 // 4096 elems
        int d = e >> 6, mm = e & 63;
        orow[(size_t)d * DM + mm] = L[mm * 72 + d];
    }
}

// W_O flat [hd][m] (f32) -> wo[m][hd] (bf16)
__global__ __launch_bounds__(256) void pack_wo(const float* __restrict__ WO, u16* __restrict__ out) {
    __shared__ u16 L[64 * 72];
    int bi = blockIdx.x, bj = blockIdx.y;    // bi: hd-tile, bj: m-tile
    int t = threadIdx.x;
    for (int j = 0; j < 4; j++) {
        int i = t + 256 * j;
        int r = i >> 4, cf = i & 15;
        float4 v = ((const float4*)(WO + (size_t)(bi * 64 + r) * DM + bj * 64))[cf];
        u16x4 o; o[0] = f2b(v.x); o[1] = f2b(v.y); o[2] = f2b(v.z); o[3] = f2b(v.w);
        *(u16x4*)&L[r * 72 + cf * 4] = o;
    }
    __syncthreads();
    for (int j = 0; j < 16; j++) {
        int e = t + 256 * j;
        int c = e >> 6, r = e & 63;          // c = m-local, r = hd-local
        out[(size_t)(bj * 64 + c) * DM + bi * 64 + r] = L[r * 72 + c];
    }
}

// ---------------- QKV GEMM:  [4096 x 768] @ [768 x 2304] -> Q/K/V [b,h,s,d] bf16 ----------------

__global__ __launch_bounds__(256) void gemm_qkv(const u16* __restrict__ A, const u16* __restrict__ Bt,
                                                const float* __restrict__ bQ, const float* __restrict__ bK,
                                                const float* __restrict__ bV,
                                                u16* __restrict__ Qb, u16* __restrict__ Kb, u16* __restrict__ Vb) {
    __shared__ u16 Al[128 * 72];
    __shared__ u16 Bl[128 * 72];
    int t = threadIdx.x;
    int n0 = blockIdx.x * 128, m0 = blockIdx.y * 128;
    int lane = t & 63, w = t >> 6;
    int ln = lane & 15, qd = lane >> 4;
    int wr = (w & 1) * 64, wc = (w >> 1) * 64;
    f32x4 acc[4][4] = {};
    for (int kt = 0; kt < DM / 64; kt++) {
        __syncthreads();
        for (int j = 0; j < 4; j++) {
            int i = t + 256 * j;             // 1024 float4s per matrix
            int r = i >> 3, cf = i & 7;
            float4 va = *(const float4*)(A + (size_t)(m0 + r) * DM + kt * 64 + cf * 8);
            *(float4*)&Al[r * 72 + cf * 8] = va;
            float4 vb = *(const float4*)(Bt + (size_t)(n0 + r) * DM + kt * 64 + cf * 8);
            *(float4*)&Bl[r * 72 + cf * 8] = vb;
        }
        __syncthreads();
        for (int ks = 0; ks < 2; ks++) {
            bf16x8 af[4], bfr[4];
            for (int rt = 0; rt < 4; rt++)
                af[rt] = *(const bf16x8*)&Al[(wr + rt * 16 + ln) * 72 + ks * 32 + qd * 8];
            for (int ct = 0; ct < 4; ct++)
                bfr[ct] = *(const bf16x8*)&Bl[(wc + ct * 16 + ln) * 72 + ks * 32 + qd * 8];
            for (int rt = 0; rt < 4; rt++)
                for (int ct = 0; ct < 4; ct++)
                    acc[rt][ct] = __builtin_amdgcn_mfma_f32_16x16x32_bf16(af[rt], bfr[ct], acc[rt][ct], 0, 0, 0);
        }
    }
    int sel = n0 / DM;                       // 128 | 768, so uniform per block
    const float* bias = sel == 0 ? bQ : (sel == 1 ? bK : bV);
    u16* Out = sel == 0 ? Qb : (sel == 1 ? Kb : Vb);
    for (int ct = 0; ct < 4; ct++) {
        int col = n0 - sel * DM + wc + ct * 16 + ln;  // hd in [0,768)
        int hh = col >> 6, dd = col & 63;
        float bv = bias[col];
        for (int rt = 0; rt < 4; rt++) {
            int row = m0 + wr + rt * 16 + qd * 4;
            for (int r = 0; r < 4; r++) {
                int rg = row + r;
                int bb = rg >> 11, ss = rg & 2047;
                Out[(((size_t)bb * NH + hh) * SLEN + ss) * DH + dd] = f2b(acc[rt][ct][r] + bv);
            }
        }
    }
}

// ---------------- fused causal attention (flash-style) ----------------
// grid: (32 q-tiles of 64, 24 bh). 4 waves, 16 q-rows each. Z out: [4096][768] bf16.

__global__ __launch_bounds__(256) void attn(const u16* __restrict__ Qb, const u16* __restrict__ Kb,
                                            const u16* __restrict__ Vb, u16* __restrict__ Zb) {
    __shared__ u16 Kl[64 * 72];
    __shared__ u16 Vt[64 * 72];
    __shared__ u16 Pl[64 * 72];
    int qt = blockIdx.x;
    int bh = blockIdx.y;
    int b = bh / NH, h = bh % NH;
    const u16* Qp = Qb + (size_t)bh * SLEN * DH;
    const u16* Kp = Kb + (size_t)bh * SLEN * DH;
    const u16* Vp = Vb + (size_t)bh * SLEN * DH;
    int t = threadIdx.x, lane = t & 63, w = t >> 6;
    int ln = lane & 15, qd = lane >> 4;
    int q0 = qt * 64, qw = q0 + w * 16;

    bf16x8 qf[2];
    for (int ks = 0; ks < 2; ks++)
        qf[ks] = *(const bf16x8*)(Qp + (size_t)(qw + ln) * DH + ks * 32 + qd * 8);

    float mrun[4], lrun[4];
    f32x4 oacc[4] = {};
    for (int r = 0; r < 4; r++) { mrun[r] = -1e30f; lrun[r] = 0.f; }

    for (int kt = 0; kt <= qt; kt++) {
        int k0 = kt * 64;
        __syncthreads();   // protect prev iteration's LDS reads
        for (int j = 0; j < 2; j++) {
            int i = t + 256 * j;             // 512 float4s
            int r = i >> 3, cf = i & 7;
            float4 kv = *(const float4*)(Kp + (size_t)(k0 + r) * DH + cf * 8);
            *(float4*)&Kl[r * 72 + cf * 8] = kv;
            float4 vv = *(const float4*)(Vp + (size_t)(k0 + r) * DH + cf * 8);
            union { float4 f; u16 u[8]; } uu; uu.f = vv;
            for (int e = 0; e < 8; e++) Vt[(cf * 8 + e) * 72 + r] = uu.u[e];  // transpose: Vt[d][kpos]
        }
        __syncthreads();

        // S = Q K^T
        f32x4 sf[4] = {};
        for (int ks = 0; ks < 2; ks++)
            for (int ct = 0; ct < 4; ct++) {
                bf16x8 kf = *(const bf16x8*)&Kl[(ct * 16 + ln) * 72 + ks * 32 + qd * 8];
                sf[ct] = __builtin_amdgcn_mfma_f32_16x16x32_bf16(qf[ks], kf, sf[ct], 0, 0, 0);
            }

        // scale + causal mask + online softmax (row = qd*4+r per wave, col = ln)
        float p[4][4], rmax[4];
        for (int r = 0; r < 4; r++) rmax[r] = -1e30f;
        for (int ct = 0; ct < 4; ct++) {
            int kc = k0 + ct * 16 + ln;
            for (int r = 0; r < 4; r++) {
                int qr = qw + qd * 4 + r;
                float v = sf[ct][r] * 0.125f;
                if (kc > qr) v = -1e30f;
                p[ct][r] = v;
                rmax[r] = fmaxf(rmax[r], v);
            }
        }
        for (int off = 1; off < 16; off <<= 1)
            for (int r = 0; r < 4; r++)
                rmax[r] = fmaxf(rmax[r], __shfl_xor(rmax[r], off, 64));
        float alpha[4], rsum[4];
        for (int r = 0; r < 4; r++) {
            float mn = fmaxf(mrun[r], rmax[r]);
            alpha[r] = __expf(mrun[r] - mn);
            mrun[r] = mn;
            float s = 0.f;
            for (int ct = 0; ct < 4; ct++) {
                float e = __expf(p[ct][r] - mn);
                p[ct][r] = e;
                s += e;
            }
            rsum[r] = s;
        }
        for (int off = 1; off < 16; off <<= 1)
            for (int r = 0; r < 4; r++)
                rsum[r] += __shfl_xor(rsum[r], off, 64);
        for (int r = 0; r < 4; r++) lrun[r] = lrun[r] * alpha[r] + rsum[r];
        for (int dt = 0; dt < 4; dt++)
            for (int r = 0; r < 4; r++)
                oacc[dt][r] *= alpha[r];

        // P (C-layout) -> LDS -> A-layout.  Per-wave private region; same-wave DS ops are in-order.
        for (int ct = 0; ct < 4; ct++)
            for (int r = 0; r < 4; r++)
                Pl[(w * 16 + qd * 4 + r) * 72 + ct * 16 + ln] = f2b(p[ct][r]);

        for (int ks = 0; ks < 2; ks++) {
            bf16x8 pf = *(const bf16x8*)&Pl[(w * 16 + ln) * 72 + ks * 32 + qd * 8];
            for (int dt = 0; dt < 4; dt++) {
                bf16x8 vf = *(const bf16x8*)&Vt[(dt * 16 + ln) * 72 + ks * 32 + qd * 8];
                oacc[dt] = __builtin_amdgcn_mfma_f32_16x16x32_bf16(pf, vf, oacc[dt], 0, 0, 0);
            }
        }
    }

    // epilogue: Z[(b*2048+s)][h*64+d] bf16
    u16* Zp = Zb + (size_t)b * SLEN * DM;
    for (int r = 0; r < 4; r++) {
        float inv = 1.0f / lrun[r];
        int qr = qw + qd * 4 + r;
        for (int dt = 0; dt < 4; dt++)
            Zp[(size_t)qr * DM + h * DH + dt * 16 + ln] = f2b(oacc[dt][r] * inv);
    }
}

// ---------------- output projection: [4096 x 768] @ [768 x 768] + b_O -> f32 ----------------

__global__ __launch_bounds__(256) void gemm_proj(const u16* __restrict__ A, const u16* __restrict__ Bt,
                                                 const float* __restrict__ bO, float* __restrict__ out) {
    __shared__ u16 Al[128 * 72];
    __shared__ u16 Bl[128 * 72];
    int t = threadIdx.x;
    int n0 = blockIdx.x * 128, m0 = blockIdx.y * 128;
    int lane = t & 63, w = t >> 6;
    int ln = lane & 15, qd = lane >> 4;
    int wr = (w & 1) * 64, wc = (w >> 1) * 64;
    f32x4 acc[4][4] = {};
    for (int kt = 0; kt < DM / 64; kt++) {
        __syncthreads();
        for (int j = 0; j < 4; j++) {
            int i = t + 256 * j;
            int r = i >> 3, cf = i & 7;
            float4 va = *(const float4*)(A + (size_t)(m0 + r) * DM + kt * 64 + cf * 8);
            *(float4*)&Al[r * 72 + cf * 8] = va;
            float4 vb = *(const float4*)(Bt + (size_t)(n0 + r) * DM + kt * 64 + cf * 8);
            *(float4*)&Bl[r * 72 + cf * 8] = vb;
        }
        __syncthreads();
        for (int ks = 0; ks < 2; ks++) {
            bf16x8 af[4], bfr[4];
            for (int rt = 0; rt < 4; rt++)
                af[rt] = *(const bf16x8*)&Al[(wr + rt * 16 + ln) * 72 + ks * 32 + qd * 8];
            for (int ct = 0; ct < 4; ct++)
                bfr[ct] = *(const bf16x8*)&Bl[(wc + ct * 16 + ln) * 72 + ks * 32 + qd * 8];
            for (int rt = 0; rt < 4; rt++)
                for (int ct = 0; ct < 4; ct++)
                    acc[rt][ct] = __builtin_amdgcn_mfma_f32_16x16x32_bf16(af[rt], bfr[ct], acc[rt][ct], 0, 0, 0);
        }
    }
    for (int ct = 0; ct < 4; ct++) {
        int col = n0 + wc + ct * 16 + ln;
        float bv = bO[col];
        for (int rt = 0; rt < 4; rt++) {
            int row = m0 + wr + rt * 16 + qd * 4;
            for (int r = 0; r < 4; r++)
                out[(size_t)(row + r) * DM + col] = acc[rt][ct][r] + bv;
        }
    }
}

// ---------------- launch ----------------

extern "C" void kernel_launch(void* const* d_in, const int* in_sizes, int n_in,
                              void* d_out, int out_size, void* d_ws, size_t ws_size,
                              hipStream_t stream) {
    const float* x  = (const float*)d_in[0];
    const float* WQ = (const float*)d_in[1];
    const float* bQ = (const float*)d_in[2];
    const float* WK = (const float*)d_in[3];
    const float* bK = (const float*)d_in[4];
    const float* WV = (const float*)d_in[5];
    const float* bV = (const float*)d_in[6];
    const float* WO = (const float*)d_in[7];
    const float* bO = (const float*)d_in[8];
    float* out = (float*)d_out;

    u16* xb   = (u16*)d_ws;                        // [4096][768]
    u16* wqkv = xb + (size_t)ROWS * DM;            // [2304][768]
    u16* wo   = wqkv + (size_t)NQKV * DM;          // [768][768]
    u16* Qb   = wo + (size_t)DM * DM;              // [2][12][2048][64]
    size_t hsz = (size_t)BATCH * NH * SLEN * DH;
    u16* Kb   = Qb + hsz;
    u16* Vb   = Kb + hsz;
    u16* Zb   = Vb + hsz;                          // [4096][768]

    pack_x<<<ROWS * DM / 2048, 256, 0, stream>>>(x, xb);
    pack_wqkv<<<dim3(12, 12, 3), 256, 0, stream>>>(WQ, WK, WV, wqkv);
    pack_wo<<<dim3(12, 12), 256, 0, stream>>>(WO, wo);
    gemm_qkv<<<dim3(NQKV / 128, ROWS / 128), 256, 0, stream>>>(xb, wqkv, bQ, bK, bV, Qb, Kb, Vb);
    attn<<<dim3(SLEN / 64, BATCH * NH), 256, 0, stream>>>(Qb, Kb, Vb, Zb);
    gemm_proj<<<dim3(DM / 128, ROWS / 128), 256, 0, stream>>>(Zb, wo, bO, out);
}